// Round 2
// baseline (13976.537 us; speedup 1.0000x reference)
//
#include <hip/hip_runtime.h>
#include <math.h>

// Problem constants (match reference)
constexpr int LYR   = 6;
constexpr int Hdim  = 1024;
constexpr int NHEAD = 16;
constexpr int DHEAD = 64;
constexpr int FFD   = 4096;
constexpr int VOC   = 50257;
constexpr int SEQ   = 1024;
constexpr int BATCH = 2;
constexpr int MTOK  = BATCH * SEQ;   // 2048 rows in the token dimension
constexpr float EPSF = 1e-6f;

// ---------------------------------------------------------------------------
// Block-wide sum reduction (blockDim.x threads, multiple of 64, <=256).
// `red` needs >= 9 floats of shared mem.
// ---------------------------------------------------------------------------
__device__ __forceinline__ float block_sum(float v, float* red) {
    __syncthreads();                       // protect red[] reuse across calls
    #pragma unroll
    for (int o = 32; o > 0; o >>= 1) v += __shfl_down(v, o, 64);
    int lane = threadIdx.x & 63, wave = threadIdx.x >> 6;
    if (lane == 0) red[wave] = v;
    __syncthreads();
    if (threadIdx.x == 0) {
        float s = 0.f;
        int nw = blockDim.x >> 6;
        for (int w = 0; w < nw; ++w) s += red[w];
        red[8] = s;
    }
    __syncthreads();
    return red[8];
}

// ---------------------------------------------------------------------------
// x = LN(tok_emb[ids] + pos_emb)  — one block per token, 256 threads.
// ---------------------------------------------------------------------------
__global__ __launch_bounds__(256) void embed_ln0_kernel(
    const int* __restrict__ ids, const float* __restrict__ tok,
    const float* __restrict__ pos, const float* __restrict__ g,
    const float* __restrict__ b, float* __restrict__ x) {
    int t = blockIdx.x;            // token index in [0, MTOK)
    int s = t % SEQ;
    int id = ids[t];
    const float* te = tok + (size_t)id * Hdim;
    const float* pe = pos + (size_t)s * Hdim;
    float vals[4];
    float sum = 0.f;
    #pragma unroll
    for (int i = 0; i < 4; ++i) {
        int c = threadIdx.x + i * 256;
        vals[i] = te[c] + pe[c];
        sum += vals[i];
    }
    __shared__ float red[9];
    float mean = block_sum(sum, red) * (1.0f / Hdim);
    float var = 0.f;
    #pragma unroll
    for (int i = 0; i < 4; ++i) { float d = vals[i] - mean; var += d * d; }
    var = block_sum(var, red) * (1.0f / Hdim);
    float inv = rsqrtf(var + EPSF);
    #pragma unroll
    for (int i = 0; i < 4; ++i) {
        int c = threadIdx.x + i * 256;
        x[(size_t)t * Hdim + c] = (vals[i] - mean) * inv * g[c] + b[c];
    }
}

// ---------------------------------------------------------------------------
// x = LN(a + x_old) * g + b   — one block per token, 256 threads, in-place on x.
// ---------------------------------------------------------------------------
__global__ __launch_bounds__(256) void add_ln_kernel(
    const float* __restrict__ a, float* __restrict__ x,
    const float* __restrict__ g, const float* __restrict__ b) {
    int t = blockIdx.x;
    float vals[4];
    float sum = 0.f;
    #pragma unroll
    for (int i = 0; i < 4; ++i) {
        int c = threadIdx.x + i * 256;
        size_t idx = (size_t)t * Hdim + c;
        vals[i] = a[idx] + x[idx];
        sum += vals[i];
    }
    __shared__ float red[9];
    float mean = block_sum(sum, red) * (1.0f / Hdim);
    float var = 0.f;
    #pragma unroll
    for (int i = 0; i < 4; ++i) { float d = vals[i] - mean; var += d * d; }
    var = block_sum(var, red) * (1.0f / Hdim);
    float inv = rsqrtf(var + EPSF);
    #pragma unroll
    for (int i = 0; i < 4; ++i) {
        int c = threadIdx.x + i * 256;
        x[(size_t)t * Hdim + c] = (vals[i] - mean) * inv * g[c] + b[c];
    }
}

// ---------------------------------------------------------------------------
// Tiled fp32 GEMM: C[M,N] = A[M,K] @ W + bias, optional exact-GELU epilogue.
// BT=0: W is [K,N] row-major.  BT=1: W is [N,K] row-major (used for lm_head,
// C = A @ W^T).  BM=BN=64, BK=16, 256 threads, 4x4 microtile per thread.
// M, K must be multiples of 64/16 (true here); N checked when BT=1.
// ---------------------------------------------------------------------------
template <int BT, int ACT>
__global__ __launch_bounds__(256) void gemm_kernel(
    const float* __restrict__ A, const float* __restrict__ W,
    const float* __restrict__ bias, float* __restrict__ C,
    int M, int N, int K) {
    constexpr int BM = 64, BN = 64, BK = 16;
    __shared__ float As[BK][BM + 4];   // +4 pad: 16B-aligned rows, conflict-light
    __shared__ float Bs[BK][BN + 4];
    const int n0 = blockIdx.x * BN;
    const int m0 = blockIdx.y * BM;
    const int tid = threadIdx.x;
    const int tx = tid & 15;           // micro-col group
    const int ty = tid >> 4;           // micro-row group
    float acc[4][4] = {};

    const int am = tid >> 2;           // 0..63
    const int ak = (tid & 3) << 2;     // 0,4,8,12

    for (int k0 = 0; k0 < K; k0 += BK) {
        // --- stage A tile (transposed into LDS) ---
        float4 av = *(const float4*)(A + (size_t)(m0 + am) * K + k0 + ak);
        As[ak + 0][am] = av.x; As[ak + 1][am] = av.y;
        As[ak + 2][am] = av.z; As[ak + 3][am] = av.w;
        // --- stage B tile ---
        if (BT) {
            int bn = tid >> 2, bkk = (tid & 3) << 2;
            float4 bv;
            if (n0 + bn < N) bv = *(const float4*)(W + (size_t)(n0 + bn) * K + k0 + bkk);
            else             bv = make_float4(0.f, 0.f, 0.f, 0.f);
            Bs[bkk + 0][bn] = bv.x; Bs[bkk + 1][bn] = bv.y;
            Bs[bkk + 2][bn] = bv.z; Bs[bkk + 3][bn] = bv.w;
        } else {
            int bkk = tid >> 4, bn = (tid & 15) << 2;
            float4 bv = *(const float4*)(W + (size_t)(k0 + bkk) * N + n0 + bn);
            *(float4*)&Bs[bkk][bn] = bv;
        }
        __syncthreads();
        #pragma unroll
        for (int k = 0; k < BK; ++k) {
            float a[4], b[4];
            #pragma unroll
            for (int i = 0; i < 4; ++i) a[i] = As[k][ty * 4 + i];
            #pragma unroll
            for (int j = 0; j < 4; ++j) b[j] = Bs[k][tx * 4 + j];
            #pragma unroll
            for (int i = 0; i < 4; ++i)
                #pragma unroll
                for (int j = 0; j < 4; ++j) acc[i][j] += a[i] * b[j];
        }
        __syncthreads();
    }

    #pragma unroll
    for (int i = 0; i < 4; ++i) {
        int m = m0 + ty * 4 + i;
        #pragma unroll
        for (int j = 0; j < 4; ++j) {
            int n = n0 + tx * 4 + j;
            if (n < N) {
                float v = acc[i][j];
                if (bias) v += bias[n];
                if (ACT == 1) v = 0.5f * v * (1.0f + erff(v * 0.70710678118654752f));
                C[(size_t)m * N + n] = v;
            }
        }
    }
}

// ---------------------------------------------------------------------------
// Causal attention, one block per (query row, head, batch). 128 threads.
// q,k,v are [B,S,H] with head h at columns [h*DH, (h+1)*DH).
// ---------------------------------------------------------------------------
__global__ __launch_bounds__(128) void attn_kernel(
    const float* __restrict__ q, const float* __restrict__ k,
    const float* __restrict__ v, float* __restrict__ ctx) {
    const int i = blockIdx.x;   // query position
    const int h = blockIdx.y;   // head
    const int b = blockIdx.z;   // batch
    const int t = threadIdx.x;

    __shared__ float qs[DHEAD];
    __shared__ float sc[SEQ];
    __shared__ float red[4 + 128];

    const size_t rowbase = ((size_t)(b * SEQ + i) * Hdim + h * DHEAD);
    if (t < DHEAD) qs[t] = q[rowbase + t];
    __syncthreads();

    const float scale = 0.125f;   // 1/sqrt(64)
    const float* kb = k + ((size_t)b * SEQ * Hdim + h * DHEAD);

    float lmax = -1e30f;
    for (int j = t; j <= i; j += 128) {
        const float* kr = kb + (size_t)j * Hdim;
        float dot = 0.f;
        #pragma unroll
        for (int d = 0; d < DHEAD; ++d) dot += qs[d] * kr[d];
        dot *= scale;
        sc[j] = dot;
        lmax = fmaxf(lmax, dot);
    }
    #pragma unroll
    for (int o = 32; o > 0; o >>= 1) lmax = fmaxf(lmax, __shfl_down(lmax, o, 64));
    int lane = t & 63, wave = t >> 6;
    if (lane == 0) red[wave] = lmax;
    __syncthreads();
    float m = fmaxf(red[0], red[1]);

    float lsum = 0.f;
    for (int j = t; j <= i; j += 128) {
        float e = expf(sc[j] - m);
        sc[j] = e;
        lsum += e;
    }
    #pragma unroll
    for (int o = 32; o > 0; o >>= 1) lsum += __shfl_down(lsum, o, 64);
    if (lane == 0) red[2 + wave] = lsum;
    __syncthreads();
    float inv = 1.0f / (red[2] + red[3]);

    // P @ V: thread t handles dim d = t&63, key parity = t>>6
    int d = t & 63, half = t >> 6;
    const float* vb = v + ((size_t)b * SEQ * Hdim + h * DHEAD + d);
    float acc = 0.f;
    for (int j = half; j <= i; j += 2) acc += sc[j] * vb[(size_t)j * Hdim];
    red[4 + t] = acc;
    __syncthreads();
    if (t < DHEAD)
        ctx[rowbase + t] = (red[4 + t] + red[4 + 64 + t]) * inv;
}

// ---------------------------------------------------------------------------
// Host-side launch
// ---------------------------------------------------------------------------
extern "C" void kernel_launch(void* const* d_in, const int* in_sizes, int n_in,
                              void* d_out, int out_size, void* d_ws, size_t ws_size,
                              hipStream_t stream) {
    const int*   ids  = (const int*)  d_in[0];
    const float* tok  = (const float*)d_in[1];
    const float* pos  = (const float*)d_in[2];
    const float* ln0g = (const float*)d_in[3];
    const float* ln0b = (const float*)d_in[4];
    const float* Wq   = (const float*)d_in[5];
    const float* bq   = (const float*)d_in[6];
    const float* Wk   = (const float*)d_in[7];
    const float* bk   = (const float*)d_in[8];
    const float* Wv   = (const float*)d_in[9];
    const float* bv   = (const float*)d_in[10];
    const float* Wo   = (const float*)d_in[11];
    const float* bo   = (const float*)d_in[12];
    const float* ln1g = (const float*)d_in[13];
    const float* ln1b = (const float*)d_in[14];
    const float* Wi   = (const float*)d_in[15];
    const float* bi   = (const float*)d_in[16];
    const float* Wf   = (const float*)d_in[17];
    const float* bf   = (const float*)d_in[18];
    const float* ln2g = (const float*)d_in[19];
    const float* ln2b = (const float*)d_in[20];
    float* out = (float*)d_out;

    // Workspace layout (floats). Total 14M floats = 56 MB.
    const size_t T = (size_t)MTOK * Hdim;     // 2M floats per activation buffer
    float* ws   = (float*)d_ws;
    float* x    = ws;                         // residual stream
    float* qb   = ws + 1 * T;                 // q
    float* kb   = ws + 2 * T;                 // k
    float* vb   = ws + 3 * T;                 // v
    float* ctx  = ws + 4 * T;                 // attention context
    float* tmp  = ws + 5 * T;                 // attn_out / ffn_out
    float* hbuf = ws + 6 * T;                 // FFN hidden: 2048*4096 = 8M floats

    dim3 blk256(256);
    dim3 gH(Hdim / 64, MTOK / 64);            // N=1024 GEMMs
    dim3 gF(FFD / 64, MTOK / 64);             // N=4096 GEMM
    dim3 gV((VOC + 63) / 64, MTOK / 64);      // lm_head (N=50257, ragged)
    dim3 gAttn(SEQ, NHEAD, BATCH);

    embed_ln0_kernel<<<MTOK, blk256, 0, stream>>>(ids, tok, pos, ln0g, ln0b, x);

    for (int l = 0; l < LYR; ++l) {
        const float* wq = Wq + (size_t)l * Hdim * Hdim;
        const float* wk = Wk + (size_t)l * Hdim * Hdim;
        const float* wv = Wv + (size_t)l * Hdim * Hdim;
        const float* wo = Wo + (size_t)l * Hdim * Hdim;
        const float* wi = Wi + (size_t)l * Hdim * FFD;
        const float* wf = Wf + (size_t)l * FFD * Hdim;

        gemm_kernel<0, 0><<<gH, blk256, 0, stream>>>(x, wq, bq + l * Hdim, qb, MTOK, Hdim, Hdim);
        gemm_kernel<0, 0><<<gH, blk256, 0, stream>>>(x, wk, bk + l * Hdim, kb, MTOK, Hdim, Hdim);
        gemm_kernel<0, 0><<<gH, blk256, 0, stream>>>(x, wv, bv + l * Hdim, vb, MTOK, Hdim, Hdim);

        attn_kernel<<<gAttn, dim3(128), 0, stream>>>(qb, kb, vb, ctx);

        gemm_kernel<0, 0><<<gH, blk256, 0, stream>>>(ctx, wo, bo + l * Hdim, tmp, MTOK, Hdim, Hdim);
        add_ln_kernel<<<MTOK, blk256, 0, stream>>>(tmp, x, ln1g + l * Hdim, ln1b + l * Hdim);

        gemm_kernel<0, 1><<<gF, blk256, 0, stream>>>(x, wi, bi + l * FFD, hbuf, MTOK, FFD, Hdim);
        gemm_kernel<0, 0><<<gH, blk256, 0, stream>>>(hbuf, wf, bf + l * Hdim, tmp, MTOK, Hdim, FFD);
        add_ln_kernel<<<MTOK, blk256, 0, stream>>>(tmp, x, ln2g + l * Hdim, ln2b + l * Hdim);
    }

    // logits = x @ tok_emb^T  (no bias)
    gemm_kernel<1, 0><<<gV, blk256, 0, stream>>>(x, tok, nullptr, out, MTOK, VOC, Hdim);
}

// Round 3
// 4709.514 us; speedup vs baseline: 2.9677x; 2.9677x over previous
//
#include <hip/hip_runtime.h>
#include <math.h>

constexpr int LYR   = 6;
constexpr int Hdim  = 1024;
constexpr int NHEAD = 16;
constexpr int DHEAD = 64;
constexpr int FFD   = 4096;
constexpr int VOC   = 50257;
constexpr int SEQ   = 1024;
constexpr int BATCH = 2;
constexpr int MTOK  = BATCH * SEQ;
constexpr float EPSF = 1e-6f;

using short8  = __attribute__((ext_vector_type(8))) short;
using floatx4 = __attribute__((ext_vector_type(4))) float;
typedef unsigned short ushortT;

// fp32 -> bf16 (RNE) and back
__device__ __forceinline__ ushortT f2bf(float f) {
    unsigned u = __float_as_uint(f);
    u += 0x7fffu + ((u >> 16) & 1u);
    return (ushortT)(u >> 16);
}
__device__ __forceinline__ float bf2f(ushortT h) {
    return __uint_as_float(((unsigned)h) << 16);
}

// ---------------------------------------------------------------------------
// block reduction helper (256 threads)
// ---------------------------------------------------------------------------
__device__ __forceinline__ float block_sum(float v, float* red) {
    __syncthreads();
    #pragma unroll
    for (int o = 32; o > 0; o >>= 1) v += __shfl_down(v, o, 64);
    int lane = threadIdx.x & 63, wave = threadIdx.x >> 6;
    if (lane == 0) red[wave] = v;
    __syncthreads();
    if (threadIdx.x == 0) red[8] = red[0] + red[1] + red[2] + red[3];
    __syncthreads();
    return red[8];
}

// ---------------------------------------------------------------------------
// Embedding + LN0; also emits bf16 hi/lo of the output (GEMM A operand).
// ---------------------------------------------------------------------------
__global__ __launch_bounds__(256) void embed_ln0_kernel(
    const int* __restrict__ ids, const float* __restrict__ tok,
    const float* __restrict__ pos, const float* __restrict__ g,
    const float* __restrict__ b, float* __restrict__ x,
    ushortT* __restrict__ xhi, ushortT* __restrict__ xlo) {
    int t = blockIdx.x;
    int s = t % SEQ;
    int id = ids[t];
    const float* te = tok + (size_t)id * Hdim;
    const float* pe = pos + (size_t)s * Hdim;
    float vals[4]; float sum = 0.f;
    #pragma unroll
    for (int i = 0; i < 4; ++i) {
        int c = threadIdx.x + i * 256;
        vals[i] = te[c] + pe[c];
        sum += vals[i];
    }
    __shared__ float red[9];
    float mean = block_sum(sum, red) * (1.0f / Hdim);
    float var = 0.f;
    #pragma unroll
    for (int i = 0; i < 4; ++i) { float d = vals[i] - mean; var += d * d; }
    var = block_sum(var, red) * (1.0f / Hdim);
    float inv = rsqrtf(var + EPSF);
    #pragma unroll
    for (int i = 0; i < 4; ++i) {
        int c = threadIdx.x + i * 256;
        float v = (vals[i] - mean) * inv * g[c] + b[c];
        size_t idx = (size_t)t * Hdim + c;
        x[idx] = v;
        ushortT h = f2bf(v);
        xhi[idx] = h;
        xlo[idx] = f2bf(v - bf2f(h));
    }
}

// ---------------------------------------------------------------------------
// x = LN(a + x); also emits bf16 hi/lo.
// ---------------------------------------------------------------------------
__global__ __launch_bounds__(256) void add_ln_kernel(
    const float* __restrict__ a, float* __restrict__ x,
    const float* __restrict__ g, const float* __restrict__ b,
    ushortT* __restrict__ xhi, ushortT* __restrict__ xlo) {
    int t = blockIdx.x;
    float vals[4]; float sum = 0.f;
    #pragma unroll
    for (int i = 0; i < 4; ++i) {
        int c = threadIdx.x + i * 256;
        size_t idx = (size_t)t * Hdim + c;
        vals[i] = a[idx] + x[idx];
        sum += vals[i];
    }
    __shared__ float red[9];
    float mean = block_sum(sum, red) * (1.0f / Hdim);
    float var = 0.f;
    #pragma unroll
    for (int i = 0; i < 4; ++i) { float d = vals[i] - mean; var += d * d; }
    var = block_sum(var, red) * (1.0f / Hdim);
    float inv = rsqrtf(var + EPSF);
    #pragma unroll
    for (int i = 0; i < 4; ++i) {
        int c = threadIdx.x + i * 256;
        float v = (vals[i] - mean) * inv * g[c] + b[c];
        size_t idx = (size_t)t * Hdim + c;
        x[idx] = v;
        ushortT h = f2bf(v);
        xhi[idx] = h;
        xlo[idx] = f2bf(v - bf2f(h));
    }
}

// ---------------------------------------------------------------------------
// Weight transpose+convert: W[K,N] fp32 -> Thi/Tlo[N,K] bf16.
// 64x64 tiles, 256 threads.
// ---------------------------------------------------------------------------
__global__ __launch_bounds__(256) void transpose_convert(
    const float* __restrict__ W, ushortT* __restrict__ Thi,
    ushortT* __restrict__ Tlo, int K, int N) {
    __shared__ float tile[64][65];
    const int n0 = blockIdx.x * 64, k0 = blockIdx.y * 64;
    const int t = threadIdx.x;
    const int rr = t >> 4, cc = (t & 15) * 4;
    #pragma unroll
    for (int it = 0; it < 4; ++it) {
        int kk = rr + it * 16;
        float4 wv = *(const float4*)&W[(size_t)(k0 + kk) * N + n0 + cc];
        tile[kk][cc + 0] = wv.x; tile[kk][cc + 1] = wv.y;
        tile[kk][cc + 2] = wv.z; tile[kk][cc + 3] = wv.w;
    }
    __syncthreads();
    #pragma unroll
    for (int it = 0; it < 4; ++it) {
        int nn = rr + it * 16;
        float f0 = tile[cc + 0][nn], f1 = tile[cc + 1][nn];
        float f2 = tile[cc + 2][nn], f3 = tile[cc + 3][nn];
        ushort4 hi, lo;
        hi.x = f2bf(f0); hi.y = f2bf(f1); hi.z = f2bf(f2); hi.w = f2bf(f3);
        lo.x = f2bf(f0 - bf2f(hi.x)); lo.y = f2bf(f1 - bf2f(hi.y));
        lo.z = f2bf(f2 - bf2f(hi.z)); lo.w = f2bf(f3 - bf2f(hi.w));
        size_t o = (size_t)(n0 + nn) * K + k0 + cc;
        *(ushort4*)&Thi[o] = hi;
        *(ushort4*)&Tlo[o] = lo;
    }
}

// ---------------------------------------------------------------------------
// MFMA GEMM with fp32 emulation via bf16 hi/lo split (3 MFMAs per tile).
// A: bf16 hi/lo [M,K].  B: bf16 hi/lo [N,K] (CONVB=0) or fp32 [N,K] (CONVB=1,
// converted in-kernel).  C = A*B^T + bias, optional exact GELU, output fp32
// or bf16 hi/lo (OUTHILO).  128x128x32 tiles, 256 threads, 4 waves in 2x2.
// ---------------------------------------------------------------------------
template <int CONVB, int ACT, int OUTHILO>
__global__ __launch_bounds__(256) void mfma_gemm(
    const ushortT* __restrict__ Ahi, const ushortT* __restrict__ Alo,
    const ushortT* __restrict__ Bhi, const ushortT* __restrict__ Blo,
    const float* __restrict__ Bf32, const float* __restrict__ bias,
    float* __restrict__ C, ushortT* __restrict__ Chi, ushortT* __restrict__ Clo,
    int M, int N, int K) {
    constexpr int BM = 128, BN = 128, BK = 32;
    constexpr int BSTR = CONVB ? 40 : 32;     // pad only when manually staged
    __shared__ __align__(16) ushortT sAhi[BM * BK], sAlo[BM * BK];
    __shared__ __align__(16) ushortT sBhi[BN * BSTR], sBlo[BN * BSTR];
    const int m0 = blockIdx.x * BM, n0 = blockIdx.y * BN;
    const int tid = threadIdx.x, wave = tid >> 6, lane = tid & 63;
    const int wr = wave >> 1, wc = wave & 1;
    const int fm = lane & 15, fk = lane >> 4;
    // staging geometry: instr j of a wave covers rows wave*32+16j+(lane>>2),
    // 16B chunk (lane&3); HW writes lane i at ldsbase + i*16 (= elem 8*i).
    const int srow = wave * 32 + (lane >> 2);
    const int scol = (lane & 3) * 8;

    floatx4 acc[4][4] = {};

    for (int k0 = 0; k0 < K; k0 += BK) {
        {
            const ushortT* g = Ahi + (size_t)(m0 + srow) * K + k0 + scol;
            __builtin_amdgcn_global_load_lds(
                (const __attribute__((address_space(1))) void*)g,
                (__attribute__((address_space(3))) void*)&sAhi[wave * 1024], 16, 0, 0);
            __builtin_amdgcn_global_load_lds(
                (const __attribute__((address_space(1))) void*)(g + 16 * (size_t)K),
                (__attribute__((address_space(3))) void*)&sAhi[wave * 1024 + 512], 16, 0, 0);
            const ushortT* gl = Alo + (size_t)(m0 + srow) * K + k0 + scol;
            __builtin_amdgcn_global_load_lds(
                (const __attribute__((address_space(1))) void*)gl,
                (__attribute__((address_space(3))) void*)&sAlo[wave * 1024], 16, 0, 0);
            __builtin_amdgcn_global_load_lds(
                (const __attribute__((address_space(1))) void*)(gl + 16 * (size_t)K),
                (__attribute__((address_space(3))) void*)&sAlo[wave * 1024 + 512], 16, 0, 0);
        }
        if (CONVB) {
            // manual stage+convert of fp32 [N,K] B tile
            int bn = tid & 127, kh = tid >> 7;
            int gn = n0 + bn; if (gn >= N) gn = N - 1;
            const float* src = Bf32 + (size_t)gn * K + k0 + kh * 16;
            ushortT* dh = &sBhi[bn * BSTR + kh * 16];
            ushortT* dl = &sBlo[bn * BSTR + kh * 16];
            #pragma unroll
            for (int p = 0; p < 4; ++p) {
                float4 vv = *(const float4*)(src + p * 4);
                ushort4 hi, lo;
                hi.x = f2bf(vv.x); hi.y = f2bf(vv.y); hi.z = f2bf(vv.z); hi.w = f2bf(vv.w);
                lo.x = f2bf(vv.x - bf2f(hi.x)); lo.y = f2bf(vv.y - bf2f(hi.y));
                lo.z = f2bf(vv.z - bf2f(hi.z)); lo.w = f2bf(vv.w - bf2f(hi.w));
                *(ushort4*)(dh + p * 4) = hi;
                *(ushort4*)(dl + p * 4) = lo;
            }
        } else {
            const ushortT* g = Bhi + (size_t)(n0 + srow) * K + k0 + scol;
            __builtin_amdgcn_global_load_lds(
                (const __attribute__((address_space(1))) void*)g,
                (__attribute__((address_space(3))) void*)&sBhi[wave * 1024], 16, 0, 0);
            __builtin_amdgcn_global_load_lds(
                (const __attribute__((address_space(1))) void*)(g + 16 * (size_t)K),
                (__attribute__((address_space(3))) void*)&sBhi[wave * 1024 + 512], 16, 0, 0);
            const ushortT* gl = Blo + (size_t)(n0 + srow) * K + k0 + scol;
            __builtin_amdgcn_global_load_lds(
                (const __attribute__((address_space(1))) void*)gl,
                (__attribute__((address_space(3))) void*)&sBlo[wave * 1024], 16, 0, 0);
            __builtin_amdgcn_global_load_lds(
                (const __attribute__((address_space(1))) void*)(gl + 16 * (size_t)K),
                (__attribute__((address_space(3))) void*)&sBlo[wave * 1024 + 512], 16, 0, 0);
        }
        __syncthreads();

        short8 ah[4], al[4], bh[4], bl[4];
        #pragma unroll
        for (int i = 0; i < 4; ++i) {
            ah[i] = *(const short8*)&sAhi[(wr * 64 + i * 16 + fm) * 32 + fk * 8];
            al[i] = *(const short8*)&sAlo[(wr * 64 + i * 16 + fm) * 32 + fk * 8];
            bh[i] = *(const short8*)&sBhi[(wc * 64 + i * 16 + fm) * BSTR + fk * 8];
            bl[i] = *(const short8*)&sBlo[(wc * 64 + i * 16 + fm) * BSTR + fk * 8];
        }
        #pragma unroll
        for (int mi = 0; mi < 4; ++mi)
            #pragma unroll
            for (int ni = 0; ni < 4; ++ni) {
                acc[mi][ni] = __builtin_amdgcn_mfma_f32_16x16x32_bf16(ah[mi], bh[ni], acc[mi][ni], 0, 0, 0);
                acc[mi][ni] = __builtin_amdgcn_mfma_f32_16x16x32_bf16(al[mi], bh[ni], acc[mi][ni], 0, 0, 0);
                acc[mi][ni] = __builtin_amdgcn_mfma_f32_16x16x32_bf16(ah[mi], bl[ni], acc[mi][ni], 0, 0, 0);
            }
        __syncthreads();
    }

    // epilogue: C/D layout col=lane&15, row=(lane>>4)*4+reg  [m89-verified]
    #pragma unroll
    for (int mi = 0; mi < 4; ++mi)
        #pragma unroll
        for (int ni = 0; ni < 4; ++ni) {
            int gn = n0 + wc * 64 + ni * 16 + fm;
            if (gn < N) {
                float bs = bias ? bias[gn] : 0.f;
                #pragma unroll
                for (int r = 0; r < 4; ++r) {
                    int gm = m0 + wr * 64 + mi * 16 + fk * 4 + r;
                    float v = acc[mi][ni][r] + bs;
                    if (ACT) v = 0.5f * v * (1.0f + erff(v * 0.70710678118654752f));
                    size_t o = (size_t)gm * N + gn;
                    if (OUTHILO) {
                        ushortT h = f2bf(v);
                        Chi[o] = h;
                        Clo[o] = f2bf(v - bf2f(h));
                    } else {
                        C[o] = v;
                    }
                }
            }
        }
}

// ---------------------------------------------------------------------------
// Flash attention, fp32 vector math. Block = (b, h, 64-query tile),
// 256 threads as 16x16 (ty=row-group, tx=col-group), 4x4 microtiles.
// Emits ctx as bf16 hi/lo (next GEMM's A operand).
// ---------------------------------------------------------------------------
__global__ __launch_bounds__(256) void flash_attn(
    const float* __restrict__ q, const float* __restrict__ k,
    const float* __restrict__ v, ushortT* __restrict__ chi,
    ushortT* __restrict__ clo) {
    const int qt = blockIdx.x, h = blockIdx.y, b = blockIdx.z;
    const int t = threadIdx.x, tx = t & 15, ty = t >> 4;
    __shared__ float Qt[64][68];   // [d][row]
    __shared__ float Kt[64][68];   // [d][col]
    __shared__ float Vs[64][68];   // [key][d]
    __shared__ float Pt[64][68];   // [key][row]
    const int q0 = qt * 64;
    const int lr = t >> 2, lq = (t & 3) * 4;

    #pragma unroll
    for (int it = 0; it < 4; ++it) {
        int d = lq + it * 16;
        float4 qv = *(const float4*)&q[((size_t)(b * SEQ + q0 + lr)) * Hdim + h * 64 + d];
        Qt[d + 0][lr] = qv.x; Qt[d + 1][lr] = qv.y;
        Qt[d + 2][lr] = qv.z; Qt[d + 3][lr] = qv.w;
    }
    float O[4][4] = {};
    float mrow[4], lrow[4];
    #pragma unroll
    for (int i = 0; i < 4; ++i) { mrow[i] = -1e30f; lrow[i] = 0.f; }

    for (int kt = 0; kt <= qt; ++kt) {
        __syncthreads();   // protect Kt/Vs/Pt from previous iteration's readers
        int k0 = kt * 64;
        #pragma unroll
        for (int it = 0; it < 4; ++it) {
            int d = lq + it * 16;
            float4 kv = *(const float4*)&k[((size_t)(b * SEQ + k0 + lr)) * Hdim + h * 64 + d];
            Kt[d + 0][lr] = kv.x; Kt[d + 1][lr] = kv.y;
            Kt[d + 2][lr] = kv.z; Kt[d + 3][lr] = kv.w;
            float4 vv = *(const float4*)&v[((size_t)(b * SEQ + k0 + lr)) * Hdim + h * 64 + d];
            *(float4*)&Vs[lr][d] = vv;
        }
        __syncthreads();

        float S[4][4] = {};
        for (int d = 0; d < 64; ++d) {
            float4 aa = *(const float4*)&Qt[d][ty * 4];
            float4 bb = *(const float4*)&Kt[d][tx * 4];
            float av[4] = {aa.x, aa.y, aa.z, aa.w};
            float bv[4] = {bb.x, bb.y, bb.z, bb.w};
            #pragma unroll
            for (int i = 0; i < 4; ++i)
                #pragma unroll
                for (int j = 0; j < 4; ++j) S[i][j] += av[i] * bv[j];
        }
        const bool diag = (kt == qt);
        #pragma unroll
        for (int i = 0; i < 4; ++i) {
            #pragma unroll
            for (int j = 0; j < 4; ++j) {
                float s = S[i][j] * 0.125f;
                if (diag && (tx * 4 + j) > (ty * 4 + i)) s = -1e30f;
                S[i][j] = s;
            }
            float rm = fmaxf(fmaxf(S[i][0], S[i][1]), fmaxf(S[i][2], S[i][3]));
            #pragma unroll
            for (int o = 1; o < 16; o <<= 1) rm = fmaxf(rm, __shfl_xor(rm, o, 64));
            float mn = fmaxf(mrow[i], rm);
            float alpha = __expf(mrow[i] - mn);
            mrow[i] = mn;
            float rs = 0.f;
            #pragma unroll
            for (int j = 0; j < 4; ++j) {
                float p = __expf(S[i][j] - mn);
                S[i][j] = p;
                rs += p;
            }
            #pragma unroll
            for (int o = 1; o < 16; o <<= 1) rs += __shfl_xor(rs, o, 64);
            lrow[i] = lrow[i] * alpha + rs;
            #pragma unroll
            for (int j = 0; j < 4; ++j) O[i][j] *= alpha;
        }
        #pragma unroll
        for (int i = 0; i < 4; ++i)
            #pragma unroll
            for (int j = 0; j < 4; ++j) Pt[tx * 4 + j][ty * 4 + i] = S[i][j];
        __syncthreads();
        for (int c = 0; c < 64; ++c) {
            float4 pp = *(const float4*)&Pt[c][ty * 4];
            float4 vv = *(const float4*)&Vs[c][tx * 4];
            float pv[4] = {pp.x, pp.y, pp.z, pp.w};
            float vvv[4] = {vv.x, vv.y, vv.z, vv.w};
            #pragma unroll
            for (int i = 0; i < 4; ++i)
                #pragma unroll
                for (int j = 0; j < 4; ++j) O[i][j] += pv[i] * vvv[j];
        }
    }

    #pragma unroll
    for (int i = 0; i < 4; ++i) {
        float inv = 1.0f / lrow[i];
        size_t base = ((size_t)(b * SEQ + q0 + ty * 4 + i)) * Hdim + h * 64 + tx * 4;
        ushort4 hh, ll;
        float o0 = O[i][0] * inv, o1 = O[i][1] * inv, o2 = O[i][2] * inv, o3 = O[i][3] * inv;
        hh.x = f2bf(o0); hh.y = f2bf(o1); hh.z = f2bf(o2); hh.w = f2bf(o3);
        ll.x = f2bf(o0 - bf2f(hh.x)); ll.y = f2bf(o1 - bf2f(hh.y));
        ll.z = f2bf(o2 - bf2f(hh.z)); ll.w = f2bf(o3 - bf2f(hh.w));
        *(ushort4*)&chi[base] = hh;
        *(ushort4*)&clo[base] = ll;
    }
}

// ---------------------------------------------------------------------------
// Host-side launch
// ---------------------------------------------------------------------------
extern "C" void kernel_launch(void* const* d_in, const int* in_sizes, int n_in,
                              void* d_out, int out_size, void* d_ws, size_t ws_size,
                              hipStream_t stream) {
    const int*   ids  = (const int*)  d_in[0];
    const float* tok  = (const float*)d_in[1];
    const float* pos  = (const float*)d_in[2];
    const float* ln0g = (const float*)d_in[3];
    const float* ln0b = (const float*)d_in[4];
    const float* Wq   = (const float*)d_in[5];
    const float* bq   = (const float*)d_in[6];
    const float* Wk   = (const float*)d_in[7];
    const float* bk   = (const float*)d_in[8];
    const float* Wv   = (const float*)d_in[9];
    const float* bv   = (const float*)d_in[10];
    const float* Wo   = (const float*)d_in[11];
    const float* bo   = (const float*)d_in[12];
    const float* ln1g = (const float*)d_in[13];
    const float* ln1b = (const float*)d_in[14];
    const float* Wi   = (const float*)d_in[15];
    const float* bi   = (const float*)d_in[16];
    const float* Wf   = (const float*)d_in[17];
    const float* bf_  = (const float*)d_in[18];
    const float* ln2g = (const float*)d_in[19];
    const float* ln2b = (const float*)d_in[20];
    float* out = (float*)d_out;

    constexpr size_t MB = 1u << 20;
    char* w = (char*)d_ws;
    float*   x    = (float*)(w + 0 * MB);      // 8 MB
    float*   tmp  = (float*)(w + 8 * MB);      // 8 MB
    float*   qb   = (float*)(w + 16 * MB);     // 8 MB
    float*   kb   = (float*)(w + 24 * MB);     // 8 MB
    float*   vb   = (float*)(w + 32 * MB);     // 8 MB
    ushortT* xhi  = (ushortT*)(w + 40 * MB);   // 4 MB
    ushortT* xlo  = (ushortT*)(w + 44 * MB);   // 4 MB
    ushortT* cthi = (ushortT*)(w + 48 * MB);   // 4 MB
    ushortT* ctlo = (ushortT*)(w + 52 * MB);   // 4 MB
    ushortT* hbhi = (ushortT*)(w + 56 * MB);   // 16 MB
    ushortT* hblo = (ushortT*)(w + 72 * MB);   // 16 MB
    ushortT* Wth  = (ushortT*)(w + 88 * MB);   // 24 MB (per-layer, rotating)
    ushortT* Wtl  = (ushortT*)(w + 112 * MB);  // 24 MB  -> total 136 MB

    const size_t OQ = 0, OK = 1048576, OV = 2097152, OO = 3145728,
                 OI = 4194304, OF = 8388608;   // offsets in Wth/Wtl (elements)

    dim3 blk256(256);
    dim3 gH(MTOK / 128, Hdim / 128);      // (m-inner, n) = (16, 8)
    dim3 gF(MTOK / 128, FFD / 128);       // (16, 32)
    dim3 gV(MTOK / 128, (VOC + 127) / 128);  // (16, 393)
    dim3 gAttn(SEQ / 64, NHEAD, BATCH);
    dim3 gT_hh(Hdim / 64, Hdim / 64);     // transpose 1024x1024
    dim3 gT_if(FFD / 64, Hdim / 64);      // Wi: K=1024,N=4096 -> grid(N/64,K/64)
    dim3 gT_fi(Hdim / 64, FFD / 64);      // Wf: K=4096,N=1024

    embed_ln0_kernel<<<MTOK, blk256, 0, stream>>>(ids, tok, pos, ln0g, ln0b, x, xhi, xlo);

    for (int l = 0; l < LYR; ++l) {
        const size_t HH = (size_t)Hdim * Hdim, HF = (size_t)Hdim * FFD;
        transpose_convert<<<gT_hh, blk256, 0, stream>>>(Wq + l * HH, Wth + OQ, Wtl + OQ, Hdim, Hdim);
        transpose_convert<<<gT_hh, blk256, 0, stream>>>(Wk + l * HH, Wth + OK, Wtl + OK, Hdim, Hdim);
        transpose_convert<<<gT_hh, blk256, 0, stream>>>(Wv + l * HH, Wth + OV, Wtl + OV, Hdim, Hdim);
        transpose_convert<<<gT_hh, blk256, 0, stream>>>(Wo + l * HH, Wth + OO, Wtl + OO, Hdim, Hdim);
        transpose_convert<<<gT_if, blk256, 0, stream>>>(Wi + l * HF, Wth + OI, Wtl + OI, Hdim, FFD);
        transpose_convert<<<gT_fi, blk256, 0, stream>>>(Wf + l * HF, Wth + OF, Wtl + OF, FFD, Hdim);

        mfma_gemm<0, 0, 0><<<gH, blk256, 0, stream>>>(xhi, xlo, Wth + OQ, Wtl + OQ, nullptr,
            bq + l * Hdim, qb, nullptr, nullptr, MTOK, Hdim, Hdim);
        mfma_gemm<0, 0, 0><<<gH, blk256, 0, stream>>>(xhi, xlo, Wth + OK, Wtl + OK, nullptr,
            bk + l * Hdim, kb, nullptr, nullptr, MTOK, Hdim, Hdim);
        mfma_gemm<0, 0, 0><<<gH, blk256, 0, stream>>>(xhi, xlo, Wth + OV, Wtl + OV, nullptr,
            bv + l * Hdim, vb, nullptr, nullptr, MTOK, Hdim, Hdim);

        flash_attn<<<gAttn, blk256, 0, stream>>>(qb, kb, vb, cthi, ctlo);

        mfma_gemm<0, 0, 0><<<gH, blk256, 0, stream>>>(cthi, ctlo, Wth + OO, Wtl + OO, nullptr,
            bo + l * Hdim, tmp, nullptr, nullptr, MTOK, Hdim, Hdim);
        add_ln_kernel<<<MTOK, blk256, 0, stream>>>(tmp, x, ln1g + l * Hdim, ln1b + l * Hdim, xhi, xlo);

        mfma_gemm<0, 1, 1><<<gF, blk256, 0, stream>>>(xhi, xlo, Wth + OI, Wtl + OI, nullptr,
            bi + l * FFD, nullptr, hbhi, hblo, MTOK, FFD, Hdim);
        mfma_gemm<0, 0, 0><<<gH, blk256, 0, stream>>>(hbhi, hblo, Wth + OF, Wtl + OF, nullptr,
            bf_ + l * Hdim, tmp, nullptr, nullptr, MTOK, Hdim, FFD);
        add_ln_kernel<<<MTOK, blk256, 0, stream>>>(tmp, x, ln2g + l * Hdim, ln2b + l * Hdim, xhi, xlo);
    }

    // logits = x @ tok_emb^T (tok is [V,H] = [N,K], converted in-kernel)
    mfma_gemm<1, 0, 0><<<gV, blk256, 0, stream>>>(xhi, xlo, nullptr, nullptr, tok,
        nullptr, out, nullptr, nullptr, MTOK, VOC, Hdim);
}